// Round 13
// baseline (197.029 us; speedup 1.0000x reference)
//
#include <hip/hip_runtime.h>
#include <cmath>

#define NN 50000
#define C_IN 256
#define C_HID 128
#define C_OUT 40

#define BSZ 512                          // nodes per bucket
#define NBUCK ((NN + BSZ - 1) / BSZ)     // 98
#define CAP 19456                        // max edges per bucket region
#define EPB 4096                         // edges per passA block

typedef __attribute__((ext_vector_type(8))) short bf16x8;
typedef __attribute__((ext_vector_type(4))) float f32x4;
typedef __attribute__((ext_vector_type(2))) float f32x2;

__device__ __forceinline__ float bf2f(unsigned int u16) {
  unsigned int b = (u16 & 0xFFFFu) << 16;
  return __builtin_bit_cast(float, b);
}
__device__ __forceinline__ unsigned short f2bf(float f) {
  unsigned int b = __builtin_bit_cast(unsigned int, f);
  unsigned int r = (b + 0x7FFF + ((b >> 16) & 1)) >> 16;  // RNE
  return (unsigned short)r;
}

// ---------------- W prep + housekeeping (zero bcur/cnt, permuted b1) ---------------------
// h1 stored layout: row pos p = c0*8 + t holds channel chan(p) = (p&7)*16 + (p>>3).

__global__ void wprep_kernel(const float* __restrict__ W1, const float* __restrict__ W2,
                             const float* __restrict__ b1, uint4* __restrict__ pbuf1,
                             uint4* __restrict__ pbuf2, float* __restrict__ bperm,
                             int* __restrict__ bcur, int* __restrict__ cnt) {
  int blk = blockIdx.x;
  int tid = threadIdx.x;
  if (blk < 16) {  // W1
    int gid = blk * 256 + tid;
    int l = gid & 63, idx = gid >> 6;  // idx = t*8+ks
    int ks = idx & 7, t = idx >> 3;
    int c = t * 16 + (l & 15);
    int kbase = ks * 32 + (l >> 4) * 8;
    unsigned int u[4];
    #pragma unroll
    for (int jp = 0; jp < 4; ++jp) {
      float v0 = W1[(size_t)(kbase + 2 * jp) * C_HID + c];
      float v1 = W1[(size_t)(kbase + 2 * jp + 1) * C_HID + c];
      u[jp] = (unsigned int)f2bf(v0) | ((unsigned int)f2bf(v1) << 16);
    }
    pbuf1[idx * 64 + l] = make_uint4(u[0], u[1], u[2], u[3]);
  } else if (blk < 19) {  // W2, k-permuted to match h1/ag1 stored order
    int gid = (blk - 16) * 256 + tid;
    int l = gid & 63, idx = gid >> 6;  // idx = t*4+ks
    int ks = idx & 3, t = idx >> 2;
    int c = t * 16 + (l & 15);
    int kbase = ks * 32 + (l >> 4) * 8;
    unsigned int u[4];
    #pragma unroll
    for (int jp = 0; jp < 4; ++jp) {
      int k0 = kbase + 2 * jp, k1 = k0 + 1;
      int ch0 = ((k0 & 7) << 4) + (k0 >> 3);
      int ch1 = ((k1 & 7) << 4) + (k1 >> 3);
      float v0 = (c < C_OUT) ? W2[(size_t)ch0 * C_OUT + c] : 0.f;
      float v1 = (c < C_OUT) ? W2[(size_t)ch1 * C_OUT + c] : 0.f;
      u[jp] = (unsigned int)f2bf(v0) | ((unsigned int)f2bf(v1) << 16);
    }
    pbuf2[idx * 64 + l] = make_uint4(u[0], u[1], u[2], u[3]);
  } else if (blk == 19) {  // zero bcur, permuted bias for agg1
    if (tid < NBUCK) bcur[tid] = 0;
    if (tid >= 128 && tid < 128 + C_HID) {
      int p = tid - 128;
      bperm[p] = b1[((p & 7) << 4) + (p >> 3)];
    }
  } else {  // zero cnt
    int i = (blk - 20) * 256 + tid;
    if (i < NN) cnt[i] = 0;
  }
}

// ---------------- Fused: GEMM1 (MFMA) + CSR pass A ---------------------------------------
// blocks < ngemm: h1[50000,128](fp8, permuted rows) = x(->bf16) @ W1
// blocks >= ngemm: LDS-binned partition of edges into NBUCK regions + global degree count.

__global__ __launch_bounds__(256) void g1passA_kernel(const float* __restrict__ x,
    const uint4* __restrict__ pb, uint2* __restrict__ h,
    const int* __restrict__ src, const int* __restrict__ dst, int E,
    unsigned int* __restrict__ gedge, int* __restrict__ bcur, int* __restrict__ cnt,
    int ngemm) {
  __shared__ unsigned int pk[EPB];
  __shared__ unsigned char bof[EPB];
  __shared__ int bcnt[NBUCK], bstart[NBUCK], bpos[NBUCK], gbase[NBUCK];
  int tid = threadIdx.x;
  if ((int)blockIdx.x < ngemm) {
    // ---- GEMM1 path (no LDS use) ----
    int l = tid & 63, w = tid >> 6;
    int row0 = blockIdx.x * 64 + w * 16;
    int arow = min(row0 + (l & 15), NN - 1);
    const float* xp = x + (size_t)arow * C_IN + (l >> 4) * 8;
    bf16x8 a[8];
    #pragma unroll
    for (int ks = 0; ks < 8; ++ks) {
      float4 a0 = *(const float4*)(xp + ks * 32);
      float4 a1 = *(const float4*)(xp + ks * 32 + 4);
      union { bf16x8 v; unsigned short s[8]; } pa;
      pa.s[0] = f2bf(a0.x); pa.s[1] = f2bf(a0.y); pa.s[2] = f2bf(a0.z); pa.s[3] = f2bf(a0.w);
      pa.s[4] = f2bf(a1.x); pa.s[5] = f2bf(a1.y); pa.s[6] = f2bf(a1.z); pa.s[7] = f2bf(a1.w);
      a[ks] = pa.v;
    }
    f32x4 acc[8] = {};
    #pragma unroll
    for (int t = 0; t < 8; ++t) {
      #pragma unroll
      for (int ks = 0; ks < 8; ++ks) {
        bf16x8 b = __builtin_bit_cast(bf16x8, pb[(t * 8 + ks) * 64 + l]);
        acc[t] = __builtin_amdgcn_mfma_f32_16x16x32_bf16(a[ks], b, acc[t], 0, 0, 0);
      }
    }
    int c0 = l & 15, rb = (l >> 4) * 4;
    #pragma unroll
    for (int r = 0; r < 4; ++r) {
      int row = row0 + rb + r;
      if (row < NN) {
        int w0 = __builtin_amdgcn_cvt_pk_fp8_f32(acc[0][r], acc[1][r], 0, false);
        w0     = __builtin_amdgcn_cvt_pk_fp8_f32(acc[2][r], acc[3][r], w0, true);
        int w1 = __builtin_amdgcn_cvt_pk_fp8_f32(acc[4][r], acc[5][r], 0, false);
        w1     = __builtin_amdgcn_cvt_pk_fp8_f32(acc[6][r], acc[7][r], w1, true);
        h[(size_t)row * 16 + c0] = make_uint2((unsigned int)w0, (unsigned int)w1);
      }
    }
    return;
  }
  // ---- passA path ----
  int e0 = (blockIdx.x - ngemm) * EPB;
  int cntE = min(EPB, E - e0);
  for (int b = tid; b < NBUCK; b += 256) bcnt[b] = 0;
  int ds_[16], ss_[16];
  __syncthreads();
  #pragma unroll
  for (int k = 0; k < 16; ++k) {
    int i = tid + k * 256;
    if (i < cntE) {
      ds_[k] = dst[e0 + i];
      ss_[k] = src[e0 + i];
      atomicAdd(&bcnt[ds_[k] >> 9], 1);
      atomicAdd(&cnt[ds_[k]], 1);       // global per-node degree
    }
  }
  __syncthreads();
  if (tid == 0) {
    int acc = 0;
    for (int b = 0; b < NBUCK; ++b) { bstart[b] = acc; bpos[b] = acc; acc += bcnt[b]; }
  }
  __syncthreads();
  #pragma unroll
  for (int k = 0; k < 16; ++k) {
    int i = tid + k * 256;
    if (i < cntE) {
      int b = ds_[k] >> 9;
      int p = atomicAdd(&bpos[b], 1);
      pk[p] = ((unsigned int)ss_[k] << 9) | (unsigned int)(ds_[k] & 511);
      bof[p] = (unsigned char)b;
    }
  }
  __syncthreads();
  for (int b = tid; b < NBUCK; b += 256)
    gbase[b] = atomicAdd(&bcur[b], bcnt[b]);
  __syncthreads();
  for (int i = tid; i < cntE; i += 256) {
    int b = bof[i];
    int p = gbase[b] + (i - bstart[b]);
    gedge[(size_t)b * CAP + p] = pk[i];
  }
}

// ---------------- pass B — per-bucket counting sort; emits packed esrc directly ----------
// epck[pos] = (src<<16) | bf16(rsqrtf(cnt[src]+1))

__global__ __launch_bounds__(512) void passB_kernel(const unsigned int* __restrict__ gedge,
    const int* __restrict__ bcur, const int* __restrict__ cnt,
    unsigned int* __restrict__ epck, int* __restrict__ off,
    float* __restrict__ dinv, int E) {
  __shared__ int dcnt[512];
  __shared__ int dsc[512];
  __shared__ int dcur[512];
  __shared__ int bc[128];
  int b = blockIdx.x, tid = threadIdx.x;
  int nE = bcur[b];
  if (tid < 128) bc[tid] = (tid < b) ? bcur[tid] : 0;
  dcnt[tid] = 0;
  __syncthreads();
  const unsigned int* reg = gedge + (size_t)b * CAP;
  for (int i = tid; i < nE; i += 512)
    atomicAdd(&dcnt[reg[i] & 511], 1);
  __syncthreads();
  for (int d = 64; d > 0; d >>= 1) {
    if (tid < d) bc[tid] += bc[tid + d];
    __syncthreads();
  }
  int base = bc[0];
  int own = dcnt[tid];
  dsc[tid] = own;
  __syncthreads();
  for (int d = 1; d < 512; d <<= 1) {
    int x = (tid >= d) ? dsc[tid - d] : 0;
    __syncthreads();
    dsc[tid] += x;
    __syncthreads();
  }
  int excl = dsc[tid] - own;
  dcur[tid] = excl;
  int node = b * BSZ + tid;
  if (node < NN) {
    off[node]  = base + excl;
    dinv[node] = rsqrtf((float)(own + 1));
  }
  if (b == 0 && tid == 0) off[NN] = E;
  __syncthreads();
  for (int i = tid; i < nE; i += 512) {
    unsigned int p = reg[i];
    int s = (int)(p >> 9);
    int pos = atomicAdd(&dcur[p & 511], 1);
    float dv = rsqrtf((float)(cnt[s] + 1));
    epck[base + pos] = ((unsigned int)s << 16) | (unsigned int)f2bf(dv);
  }
}

// ---------------- GEMM 2 (MFMA): h2[50000,40](fp8) = ag1(bf16, stored order) @ W2 --------

__global__ __launch_bounds__(256) void gemm2_kernel(const unsigned short* __restrict__ ag1b,
    const uint4* __restrict__ pbuf, unsigned char* __restrict__ h2) {
  int l = threadIdx.x & 63, w = threadIdx.x >> 6;
  int row0 = blockIdx.x * 64 + w * 16;
  int arow = min(row0 + (l & 15), NN - 1);
  const uint4* ap = (const uint4*)(ag1b + (size_t)arow * C_HID + (l >> 4) * 8);
  bf16x8 a[4];
  #pragma unroll
  for (int ks = 0; ks < 4; ++ks) a[ks] = __builtin_bit_cast(bf16x8, ap[ks * 4]);
  f32x4 acc[3] = {};
  #pragma unroll
  for (int t = 0; t < 3; ++t) {
    #pragma unroll
    for (int ks = 0; ks < 4; ++ks) {
      bf16x8 b = __builtin_bit_cast(bf16x8, pbuf[(t * 4 + ks) * 64 + l]);
      acc[t] = __builtin_amdgcn_mfma_f32_16x16x32_bf16(a[ks], b, acc[t], 0, 0, 0);
    }
  }
  int rbase = row0 + (l >> 4) * 4;
  int c0 = l & 15;
  #pragma unroll
  for (int t = 0; t < 3; ++t) {
    int col = t * 16 + c0;
    if (col < C_OUT) {
      #pragma unroll
      for (int r = 0; r < 4; ++r) {
        int row = rbase + r;
        if (row < NN) {
          int pk = __builtin_amdgcn_cvt_pk_fp8_f32(acc[t][r], 0.f, 0, false);
          h2[(size_t)row * C_OUT + col] = (unsigned char)(pk & 0xFF);
        }
      }
    }
  }
}

// ---------------- Aggregation ----------------

// Layer-1 agg: wave per node, 16 lanes/edge (uint2 = 8 fp8 ch), 16 edges/iter,
// 2-level pipeline. Output bf16 in same stored order.
__global__ void agg1_kernel(const uint2* __restrict__ h, const int* __restrict__ off,
                            const unsigned int* __restrict__ epack,
                            const float* __restrict__ dinv, const float* __restrict__ bperm,
                            uint4* __restrict__ outb, int n, int E) {
  int wv = threadIdx.x >> 6, l = threadIdx.x & 63;
  int i = blockIdx.x * 4 + wv;
  if (i >= n) return;
  int g = l >> 4, q = l & 15;
  float di = dinv[i];
  float a0 = 0.f, a1 = 0.f, a2 = 0.f, a3 = 0.f, a4 = 0.f, a5 = 0.f, a6 = 0.f, a7 = 0.f;
  int p0 = off[i], p1 = off[i + 1];
  int pb = p0;
  int Em1 = E - 1;
  unsigned int e0 = epack[min(pb + g, Em1)];
  unsigned int e1 = epack[min(pb + 4 + g, Em1)];
  unsigned int e2 = epack[min(pb + 8 + g, Em1)];
  unsigned int e3 = epack[min(pb + 12 + g, Em1)];
  unsigned int f0 = epack[min(pb + 16 + g, Em1)];
  unsigned int f1 = epack[min(pb + 20 + g, Em1)];
  unsigned int f2 = epack[min(pb + 24 + g, Em1)];
  unsigned int f3 = epack[min(pb + 28 + g, Em1)];
  uint2 H0 = h[(size_t)(e0 >> 16) * 16 + q];
  uint2 H1 = h[(size_t)(e1 >> 16) * 16 + q];
  uint2 H2 = h[(size_t)(e2 >> 16) * 16 + q];
  uint2 H3 = h[(size_t)(e3 >> 16) * 16 + q];
  #define ACC_EDGE(vv, ee)                                                    \
    {                                                                         \
      float n_ = bf2f(ee) * di;                                               \
      f32x2 c0_ = __builtin_amdgcn_cvt_pk_f32_fp8((int)vv.x, false);          \
      f32x2 c1_ = __builtin_amdgcn_cvt_pk_f32_fp8((int)vv.x, true);           \
      f32x2 c2_ = __builtin_amdgcn_cvt_pk_f32_fp8((int)vv.y, false);          \
      f32x2 c3_ = __builtin_amdgcn_cvt_pk_f32_fp8((int)vv.y, true);           \
      a0 += c0_[0] * n_; a1 += c0_[1] * n_;                                   \
      a2 += c1_[0] * n_; a3 += c1_[1] * n_;                                   \
      a4 += c2_[0] * n_; a5 += c2_[1] * n_;                                   \
      a6 += c3_[0] * n_; a7 += c3_[1] * n_;                                   \
    }
  for (; pb + 31 < p1; pb += 16) {
    uint2 G0 = h[(size_t)(f0 >> 16) * 16 + q];
    uint2 G1 = h[(size_t)(f1 >> 16) * 16 + q];
    uint2 G2 = h[(size_t)(f2 >> 16) * 16 + q];
    uint2 G3 = h[(size_t)(f3 >> 16) * 16 + q];
    unsigned int n0 = epack[min(pb + 32 + g, Em1)];
    unsigned int n1 = epack[min(pb + 36 + g, Em1)];
    unsigned int n2 = epack[min(pb + 40 + g, Em1)];
    unsigned int n3 = epack[min(pb + 44 + g, Em1)];
    ACC_EDGE(H0, e0); ACC_EDGE(H1, e1); ACC_EDGE(H2, e2); ACC_EDGE(H3, e3);
    e0 = f0; e1 = f1; e2 = f2; e3 = f3;
    f0 = n0; f1 = n1; f2 = n2; f3 = n3;
    H0 = G0; H1 = G1; H2 = G2; H3 = G3;
  }
  if (pb + g < p1)      ACC_EDGE(H0, e0);
  if (pb + 4 + g < p1)  ACC_EDGE(H1, e1);
  if (pb + 8 + g < p1)  ACC_EDGE(H2, e2);
  if (pb + 12 + g < p1) ACC_EDGE(H3, e3);
  int pc = pb + 16;
  if (pc < p1) {
    uint2 G0 = h[(size_t)(f0 >> 16) * 16 + q];
    uint2 G1 = h[(size_t)(f1 >> 16) * 16 + q];
    uint2 G2 = h[(size_t)(f2 >> 16) * 16 + q];
    uint2 G3 = h[(size_t)(f3 >> 16) * 16 + q];
    if (pc + g < p1)      ACC_EDGE(G0, f0);
    if (pc + 4 + g < p1)  ACC_EDGE(G1, f1);
    if (pc + 8 + g < p1)  ACC_EDGE(G2, f2);
    if (pc + 12 + g < p1) ACC_EDGE(G3, f3);
  }
  #undef ACC_EDGE
  a0 += __shfl_xor(a0, 16); a1 += __shfl_xor(a1, 16);
  a2 += __shfl_xor(a2, 16); a3 += __shfl_xor(a3, 16);
  a4 += __shfl_xor(a4, 16); a5 += __shfl_xor(a5, 16);
  a6 += __shfl_xor(a6, 16); a7 += __shfl_xor(a7, 16);
  a0 += __shfl_xor(a0, 32); a1 += __shfl_xor(a1, 32);
  a2 += __shfl_xor(a2, 32); a3 += __shfl_xor(a3, 32);
  a4 += __shfl_xor(a4, 32); a5 += __shfl_xor(a5, 32);
  a6 += __shfl_xor(a6, 32); a7 += __shfl_xor(a7, 32);
  if (g == 0) {
    uint2 sv = h[(size_t)i * 16 + q];
    float dd = di * di;
    f32x2 s0 = __builtin_amdgcn_cvt_pk_f32_fp8((int)sv.x, false);
    f32x2 s1 = __builtin_amdgcn_cvt_pk_f32_fp8((int)sv.x, true);
    f32x2 s2 = __builtin_amdgcn_cvt_pk_f32_fp8((int)sv.y, false);
    f32x2 s3 = __builtin_amdgcn_cvt_pk_f32_fp8((int)sv.y, true);
    a0 += s0[0] * dd; a1 += s0[1] * dd;
    a2 += s1[0] * dd; a3 += s1[1] * dd;
    a4 += s2[0] * dd; a5 += s2[1] * dd;
    a6 += s3[0] * dd; a7 += s3[1] * dd;
    float4 b0 = ((const float4*)bperm)[q * 2];
    float4 b1v = ((const float4*)bperm)[q * 2 + 1];
    a0 = fmaxf(a0 + b0.x, 0.f); a1 = fmaxf(a1 + b0.y, 0.f);
    a2 = fmaxf(a2 + b0.z, 0.f); a3 = fmaxf(a3 + b0.w, 0.f);
    a4 = fmaxf(a4 + b1v.x, 0.f); a5 = fmaxf(a5 + b1v.y, 0.f);
    a6 = fmaxf(a6 + b1v.z, 0.f); a7 = fmaxf(a7 + b1v.w, 0.f);
    uint4 o;
    o.x = (unsigned int)f2bf(a0) | ((unsigned int)f2bf(a1) << 16);
    o.y = (unsigned int)f2bf(a2) | ((unsigned int)f2bf(a3) << 16);
    o.z = (unsigned int)f2bf(a4) | ((unsigned int)f2bf(a5) << 16);
    o.w = (unsigned int)f2bf(a6) | ((unsigned int)f2bf(a7) << 16);
    outb[(size_t)i * 16 + q] = o;
  }
}

// Layer-2 agg + bias + log_softmax: wave per node, fp8 h2 (uint = 4 ch/lane, 10 lanes/edge),
// 12 edges/iter via 2 gathers, 2-level pipeline.
__global__ void agg2_kernel(const unsigned char* __restrict__ h2, const int* __restrict__ off,
                            const unsigned int* __restrict__ epack,
                            const float* __restrict__ dinv, const float* __restrict__ b,
                            float* __restrict__ out, int n, int E) {
  int wv = threadIdx.x >> 6, l = threadIdx.x & 63;
  int i = blockIdx.x * 4 + wv;
  if (i >= n) return;
  int g = l / 10, q = l - g * 10;
  bool lact = l < 60;
  if (!lact) { g = 0; q = 0; }
  float di = dinv[i];
  float a0 = 0.f, a1 = 0.f, a2 = 0.f, a3 = 0.f;
  int p0 = off[i], p1 = off[i + 1];
  int pb = p0;
  int Em1 = E - 1;
  unsigned int e0 = epack[min(pb + g, Em1)];
  unsigned int e1 = epack[min(pb + 6 + g, Em1)];
  unsigned int f0 = epack[min(pb + 12 + g, Em1)];
  unsigned int f1 = epack[min(pb + 18 + g, Em1)];
  unsigned int H0 = *(const unsigned int*)(h2 + (size_t)(e0 >> 16) * C_OUT + q * 4);
  unsigned int H1 = *(const unsigned int*)(h2 + (size_t)(e1 >> 16) * C_OUT + q * 4);
  #define ACC_EDGE2(vv, ee)                                                   \
    {                                                                         \
      float n_ = bf2f(ee) * di;                                               \
      f32x2 lo_ = __builtin_amdgcn_cvt_pk_f32_fp8((int)(vv), false);          \
      f32x2 hi_ = __builtin_amdgcn_cvt_pk_f32_fp8((int)(vv), true);           \
      a0 += lo_[0] * n_; a1 += lo_[1] * n_;                                   \
      a2 += hi_[0] * n_; a3 += hi_[1] * n_;                                   \
    }
  for (; pb + 23 < p1; pb += 12) {
    unsigned int G0 = *(const unsigned int*)(h2 + (size_t)(f0 >> 16) * C_OUT + q * 4);
    unsigned int G1 = *(const unsigned int*)(h2 + (size_t)(f1 >> 16) * C_OUT + q * 4);
    unsigned int n0 = epack[min(pb + 24 + g, Em1)];
    unsigned int n1 = epack[min(pb + 30 + g, Em1)];
    if (lact) { ACC_EDGE2(H0, e0); ACC_EDGE2(H1, e1); }
    e0 = f0; e1 = f1;
    f0 = n0; f1 = n1;
    H0 = G0; H1 = G1;
  }
  if (lact && pb + g < p1)     ACC_EDGE2(H0, e0);
  if (lact && pb + 6 + g < p1) ACC_EDGE2(H1, e1);
  int pc = pb + 12;
  if (pc < p1) {
    unsigned int G0 = *(const unsigned int*)(h2 + (size_t)(f0 >> 16) * C_OUT + q * 4);
    unsigned int G1 = *(const unsigned int*)(h2 + (size_t)(f1 >> 16) * C_OUT + q * 4);
    if (lact && pc + g < p1)     ACC_EDGE2(G0, f0);
    if (lact && pc + 6 + g < p1) ACC_EDGE2(G1, f1);
  }
  #undef ACC_EDGE2
  float t0 = 0.f, t1 = 0.f, t2 = 0.f, t3 = 0.f;
  #pragma unroll
  for (int gg = 0; gg < 6; ++gg) {
    int sl = gg * 10 + q;
    t0 += __shfl(a0, sl); t1 += __shfl(a1, sl);
    t2 += __shfl(a2, sl); t3 += __shfl(a3, sl);
  }
  bool act = l < 10;
  float v0, v1, v2, v3;
  if (act) {
    unsigned int sv = *(const unsigned int*)(h2 + (size_t)i * C_OUT + l * 4);
    f32x2 slo = __builtin_amdgcn_cvt_pk_f32_fp8((int)sv, false);
    f32x2 shi = __builtin_amdgcn_cvt_pk_f32_fp8((int)sv, true);
    float dd = di * di;
    float4 bb = ((const float4*)b)[l];
    v0 = t0 + slo[0] * dd + bb.x;
    v1 = t1 + slo[1] * dd + bb.y;
    v2 = t2 + shi[0] * dd + bb.z;
    v3 = t3 + shi[1] * dd + bb.w;
  } else {
    v0 = v1 = v2 = v3 = -INFINITY;
  }
  float mm = fmaxf(fmaxf(v0, v1), fmaxf(v2, v3));
  #pragma unroll
  for (int d = 32; d > 0; d >>= 1) mm = fmaxf(mm, __shfl_xor(mm, d));
  float e = act ? (expf(v0 - mm) + expf(v1 - mm) + expf(v2 - mm) + expf(v3 - mm)) : 0.f;
  float ss = e;
  #pragma unroll
  for (int d = 32; d > 0; d >>= 1) ss += __shfl_xor(ss, d);
  if (act) {
    float lg = logf(ss);
    float4 o = {v0 - mm - lg, v1 - mm - lg, v2 - mm - lg, v3 - mm - lg};
    *(float4*)&out[(size_t)i * C_OUT + l * 4] = o;
  }
}

// ---------------- launch ----------------

extern "C" void kernel_launch(void* const* d_in, const int* in_sizes, int n_in,
                              void* d_out, int out_size, void* d_ws, size_t ws_size,
                              hipStream_t stream) {
  const float* x  = (const float*)d_in[0];
  const int*   ei = (const int*)d_in[1];
  const float* W1 = (const float*)d_in[2];
  const float* b1 = (const float*)d_in[3];
  const float* W2 = (const float*)d_in[4];
  const float* b2 = (const float*)d_in[5];
  int E = in_sizes[1] / 2;
  const int* src = ei;
  const int* dst = ei + E;

  char* ws = (char*)d_ws;
  size_t o = 0;
  auto alloc = [&](size_t bytes) {
    char* p = ws + o;
    o += (bytes + 255) & ~(size_t)255;
    return p;
  };
  unsigned int* gedge = (unsigned int*)alloc((size_t)NBUCK * CAP * sizeof(unsigned int));
  int*   bcur  = (int*)alloc(NBUCK * sizeof(int));
  int*   cnt   = (int*)alloc(NN * sizeof(int));
  int*   off   = (int*)alloc((NN + 1) * sizeof(int));
  float* dinv  = (float*)alloc(NN * sizeof(float));
  unsigned int* epck = (unsigned int*)alloc((size_t)E * sizeof(unsigned int));
  uint2* h1f8  = (uint2*)alloc((size_t)NN * C_HID);      // fp8, 128 B/row
  unsigned int*   ag1b = (unsigned int*)alloc((size_t)NN * (C_HID / 2) * sizeof(unsigned int));
  unsigned char*  h2f8 = (unsigned char*)alloc((size_t)NN * C_OUT);  // fp8, 40 B/row
  uint4* pbuf2 = (uint4*)alloc(12 * 64 * sizeof(uint4));
  uint4* pbuf1 = (uint4*)alloc(64 * 64 * sizeof(uint4));
  float* bperm = (float*)alloc(C_HID * sizeof(float));

  int ngemm = (NN + 63) / 64;            // 782
  int nA = (E + EPB - 1) / EPB;          // 391
  int nzero = (NN + 255) / 256;          // 196

  wprep_kernel<<<20 + nzero, 256, 0, stream>>>(W1, W2, b1, pbuf1, pbuf2, bperm, bcur, cnt);
  g1passA_kernel<<<ngemm + nA, 256, 0, stream>>>(x, pbuf1, h1f8, src, dst, E,
                                                 gedge, bcur, cnt, ngemm);
  passB_kernel<<<NBUCK, 512, 0, stream>>>(gedge, bcur, cnt, epck, off, dinv, E);
  agg1_kernel<<<(NN + 3) / 4, 256, 0, stream>>>(h1f8, off, epck, dinv, bperm,
                                                (uint4*)ag1b, NN, E);
  gemm2_kernel<<<ngemm, 256, 0, stream>>>((const unsigned short*)ag1b, pbuf2, h2f8);
  agg2_kernel<<<(NN + 3) / 4, 256, 0, stream>>>(h2f8, off, epck, dinv, b2,
                                                (float*)d_out, NN, E);
}

// Round 14
// 132.976 us; speedup vs baseline: 1.4817x; 1.4817x over previous
//
#include <hip/hip_runtime.h>
#include <cmath>

#define NN 50000
#define C_IN 256
#define C_HID 128
#define C_OUT 40

#define BSZ 512                          // nodes per bucket
#define NBUCK ((NN + BSZ - 1) / BSZ)     // 98
#define CAP 19456                        // max edges per bucket region
#define EPB 4096                         // edges per passA block

typedef __attribute__((ext_vector_type(8))) short bf16x8;
typedef __attribute__((ext_vector_type(4))) float f32x4;
typedef __attribute__((ext_vector_type(2))) float f32x2;

__device__ __forceinline__ float bf2f(unsigned int u16) {
  unsigned int b = (u16 & 0xFFFFu) << 16;
  return __builtin_bit_cast(float, b);
}
__device__ __forceinline__ unsigned short f2bf(float f) {
  unsigned int b = __builtin_bit_cast(unsigned int, f);
  unsigned int r = (b + 0x7FFF + ((b >> 16) & 1)) >> 16;  // RNE
  return (unsigned short)r;
}

// ---------------- Fused: W prep (+permuted b1) ∥ CSR pass A ------------------------------
// blocks 0-15: W1 frags; 16-18: W2 frags (k-permuted); 19: bperm; 20+: passA.
// bcur must be zeroed before this launch (memset). NO global cnt atomics (R13 lesson).
// h1 stored layout: row pos p = c0*8 + t holds channel chan(p) = (p&7)*16 + (p>>3).

__global__ __launch_bounds__(256) void prep_passA_kernel(const float* __restrict__ W1,
    const float* __restrict__ W2, const float* __restrict__ b1,
    uint4* __restrict__ pbuf1, uint4* __restrict__ pbuf2, float* __restrict__ bperm,
    const int* __restrict__ src, const int* __restrict__ dst, int E,
    unsigned int* __restrict__ gedge, int* __restrict__ bcur) {
  __shared__ unsigned int pk[EPB];
  __shared__ unsigned char bof[EPB];
  __shared__ int bcnt[NBUCK], bstart[NBUCK], bpos[NBUCK], gbase[NBUCK];
  int blk = blockIdx.x;
  int tid = threadIdx.x;
  if (blk < 16) {  // W1
    int gid = blk * 256 + tid;
    int l = gid & 63, idx = gid >> 6;  // idx = t*8+ks
    int ks = idx & 7, t = idx >> 3;
    int c = t * 16 + (l & 15);
    int kbase = ks * 32 + (l >> 4) * 8;
    unsigned int u[4];
    #pragma unroll
    for (int jp = 0; jp < 4; ++jp) {
      float v0 = W1[(size_t)(kbase + 2 * jp) * C_HID + c];
      float v1 = W1[(size_t)(kbase + 2 * jp + 1) * C_HID + c];
      u[jp] = (unsigned int)f2bf(v0) | ((unsigned int)f2bf(v1) << 16);
    }
    pbuf1[idx * 64 + l] = make_uint4(u[0], u[1], u[2], u[3]);
    return;
  } else if (blk < 19) {  // W2, k-permuted to match h1/ag1 stored order
    int gid = (blk - 16) * 256 + tid;
    int l = gid & 63, idx = gid >> 6;  // idx = t*4+ks
    int ks = idx & 3, t = idx >> 2;
    int c = t * 16 + (l & 15);
    int kbase = ks * 32 + (l >> 4) * 8;
    unsigned int u[4];
    #pragma unroll
    for (int jp = 0; jp < 4; ++jp) {
      int k0 = kbase + 2 * jp, k1 = k0 + 1;
      int ch0 = ((k0 & 7) << 4) + (k0 >> 3);
      int ch1 = ((k1 & 7) << 4) + (k1 >> 3);
      float v0 = (c < C_OUT) ? W2[(size_t)ch0 * C_OUT + c] : 0.f;
      float v1 = (c < C_OUT) ? W2[(size_t)ch1 * C_OUT + c] : 0.f;
      u[jp] = (unsigned int)f2bf(v0) | ((unsigned int)f2bf(v1) << 16);
    }
    pbuf2[idx * 64 + l] = make_uint4(u[0], u[1], u[2], u[3]);
    return;
  } else if (blk == 19) {  // permuted bias for agg1
    if (tid < C_HID) bperm[tid] = b1[((tid & 7) << 4) + (tid >> 3)];
    return;
  }
  // ---- passA path (LDS-binned partition; LDS atomics only) ----
  int e0 = (blk - 20) * EPB;
  int cntE = min(EPB, E - e0);
  for (int b = tid; b < NBUCK; b += 256) bcnt[b] = 0;
  int ds_[16], ss_[16];
  __syncthreads();
  #pragma unroll
  for (int k = 0; k < 16; ++k) {
    int i = tid + k * 256;
    if (i < cntE) {
      ds_[k] = dst[e0 + i];
      ss_[k] = src[e0 + i];
      atomicAdd(&bcnt[ds_[k] >> 9], 1);
    }
  }
  __syncthreads();
  if (tid == 0) {
    int acc = 0;
    for (int b = 0; b < NBUCK; ++b) { bstart[b] = acc; bpos[b] = acc; acc += bcnt[b]; }
  }
  __syncthreads();
  #pragma unroll
  for (int k = 0; k < 16; ++k) {
    int i = tid + k * 256;
    if (i < cntE) {
      int b = ds_[k] >> 9;
      int p = atomicAdd(&bpos[b], 1);
      pk[p] = ((unsigned int)ss_[k] << 9) | (unsigned int)(ds_[k] & 511);
      bof[p] = (unsigned char)b;
    }
  }
  __syncthreads();
  for (int b = tid; b < NBUCK; b += 256)
    gbase[b] = atomicAdd(&bcur[b], bcnt[b]);
  __syncthreads();
  for (int i = tid; i < cntE; i += 256) {
    int b = bof[i];
    int p = gbase[b] + (i - bstart[b]);
    gedge[(size_t)b * CAP + p] = pk[i];
  }
}

// ---------------- Fused: pass B (counting sort) ∥ GEMM1 (MFMA) ---------------------------
// blocks 0..NBUCK-1: per-bucket counting sort -> esrc, off, dinv.
// blocks NBUCK..: gemm1, 8 waves x 16 rows = 128 rows/block.

__global__ __launch_bounds__(512) void passB_g1_kernel(const unsigned int* __restrict__ gedge,
    const int* __restrict__ bcur, int* __restrict__ esrc, int* __restrict__ off,
    float* __restrict__ dinv, int E,
    const float* __restrict__ x, const uint4* __restrict__ pb, uint2* __restrict__ h) {
  __shared__ int dcnt[512];
  __shared__ int dsc[512];
  __shared__ int dcur[512];
  __shared__ int bc[128];
  int tid = threadIdx.x;
  if ((int)blockIdx.x >= NBUCK) {
    // ---- GEMM1 path ----
    int l = tid & 63, w = tid >> 6;  // 8 waves
    int row0 = (blockIdx.x - NBUCK) * 128 + w * 16;
    int arow = min(row0 + (l & 15), NN - 1);
    const float* xp = x + (size_t)arow * C_IN + (l >> 4) * 8;
    bf16x8 a[8];
    #pragma unroll
    for (int ks = 0; ks < 8; ++ks) {
      float4 a0 = *(const float4*)(xp + ks * 32);
      float4 a1 = *(const float4*)(xp + ks * 32 + 4);
      union { bf16x8 v; unsigned short s[8]; } pa;
      pa.s[0] = f2bf(a0.x); pa.s[1] = f2bf(a0.y); pa.s[2] = f2bf(a0.z); pa.s[3] = f2bf(a0.w);
      pa.s[4] = f2bf(a1.x); pa.s[5] = f2bf(a1.y); pa.s[6] = f2bf(a1.z); pa.s[7] = f2bf(a1.w);
      a[ks] = pa.v;
    }
    f32x4 acc[8] = {};
    #pragma unroll
    for (int t = 0; t < 8; ++t) {
      #pragma unroll
      for (int ks = 0; ks < 8; ++ks) {
        bf16x8 b = __builtin_bit_cast(bf16x8, pb[(t * 8 + ks) * 64 + l]);
        acc[t] = __builtin_amdgcn_mfma_f32_16x16x32_bf16(a[ks], b, acc[t], 0, 0, 0);
      }
    }
    int c0 = l & 15, rb = (l >> 4) * 4;
    #pragma unroll
    for (int r = 0; r < 4; ++r) {
      int row = row0 + rb + r;
      if (row < NN) {
        int w0 = __builtin_amdgcn_cvt_pk_fp8_f32(acc[0][r], acc[1][r], 0, false);
        w0     = __builtin_amdgcn_cvt_pk_fp8_f32(acc[2][r], acc[3][r], w0, true);
        int w1 = __builtin_amdgcn_cvt_pk_fp8_f32(acc[4][r], acc[5][r], 0, false);
        w1     = __builtin_amdgcn_cvt_pk_fp8_f32(acc[6][r], acc[7][r], w1, true);
        h[(size_t)row * 16 + c0] = make_uint2((unsigned int)w0, (unsigned int)w1);
      }
    }
    return;
  }
  // ---- passB path ----
  int b = blockIdx.x;
  int nE = bcur[b];
  if (tid < 128) bc[tid] = (tid < b) ? bcur[tid] : 0;
  dcnt[tid] = 0;
  __syncthreads();
  const unsigned int* reg = gedge + (size_t)b * CAP;
  for (int i = tid; i < nE; i += 512)
    atomicAdd(&dcnt[reg[i] & 511], 1);
  __syncthreads();
  for (int d = 64; d > 0; d >>= 1) {  // tree-reduce bc -> base
    if (tid < d) bc[tid] += bc[tid + d];
    __syncthreads();
  }
  int base = bc[0];
  int own = dcnt[tid];
  dsc[tid] = own;
  __syncthreads();
  for (int d = 1; d < 512; d <<= 1) {
    int x_ = (tid >= d) ? dsc[tid - d] : 0;
    __syncthreads();
    dsc[tid] += x_;
    __syncthreads();
  }
  int excl = dsc[tid] - own;
  dcur[tid] = excl;
  int node = b * BSZ + tid;
  if (node < NN) {
    off[node]  = base + excl;
    dinv[node] = rsqrtf((float)(own + 1));
  }
  if (b == 0 && tid == 0) off[NN] = E;
  __syncthreads();
  for (int i = tid; i < nE; i += 512) {
    unsigned int p = reg[i];
    int pos = atomicAdd(&dcur[p & 511], 1);
    esrc[base + pos] = (int)(p >> 9);
  }
}

// epack[e] = (src<<16) | bf16(dinv[src])
__global__ void epack_kernel(const int* __restrict__ esrc, const float* __restrict__ dinv,
                             unsigned int* __restrict__ epack, int E) {
  int e = blockIdx.x * 256 + threadIdx.x;
  if (e < E) {
    int s = esrc[e];
    epack[e] = ((unsigned int)s << 16) | (unsigned int)f2bf(dinv[s]);
  }
}

// ---------------- GEMM 2 (MFMA): h2[50000,40](fp8) = ag1(bf16, stored order) @ W2 --------

__global__ __launch_bounds__(256) void gemm2_kernel(const unsigned short* __restrict__ ag1b,
    const uint4* __restrict__ pbuf, unsigned char* __restrict__ h2) {
  int l = threadIdx.x & 63, w = threadIdx.x >> 6;
  int row0 = blockIdx.x * 64 + w * 16;
  int arow = min(row0 + (l & 15), NN - 1);
  const uint4* ap = (const uint4*)(ag1b + (size_t)arow * C_HID + (l >> 4) * 8);
  bf16x8 a[4];
  #pragma unroll
  for (int ks = 0; ks < 4; ++ks) a[ks] = __builtin_bit_cast(bf16x8, ap[ks * 4]);
  f32x4 acc[3] = {};
  #pragma unroll
  for (int t = 0; t < 3; ++t) {
    #pragma unroll
    for (int ks = 0; ks < 4; ++ks) {
      bf16x8 b = __builtin_bit_cast(bf16x8, pbuf[(t * 4 + ks) * 64 + l]);
      acc[t] = __builtin_amdgcn_mfma_f32_16x16x32_bf16(a[ks], b, acc[t], 0, 0, 0);
    }
  }
  int rbase = row0 + (l >> 4) * 4;
  int c0 = l & 15;
  #pragma unroll
  for (int t = 0; t < 3; ++t) {
    int col = t * 16 + c0;
    if (col < C_OUT) {
      #pragma unroll
      for (int r = 0; r < 4; ++r) {
        int row = rbase + r;
        if (row < NN) {
          int pk = __builtin_amdgcn_cvt_pk_fp8_f32(acc[t][r], 0.f, 0, false);
          h2[(size_t)row * C_OUT + col] = (unsigned char)(pk & 0xFF);
        }
      }
    }
  }
}

// ---------------- Aggregation ----------------

// Layer-1 agg: wave per node, 16 lanes/edge (uint2 = 8 fp8 ch), 16 edges/iter,
// 2-level pipeline. Output bf16 in same stored order.
__global__ void agg1_kernel(const uint2* __restrict__ h, const int* __restrict__ off,
                            const unsigned int* __restrict__ epack,
                            const float* __restrict__ dinv, const float* __restrict__ bperm,
                            uint4* __restrict__ outb, int n, int E) {
  int wv = threadIdx.x >> 6, l = threadIdx.x & 63;
  int i = blockIdx.x * 4 + wv;
  if (i >= n) return;
  int g = l >> 4, q = l & 15;
  float di = dinv[i];
  float a0 = 0.f, a1 = 0.f, a2 = 0.f, a3 = 0.f, a4 = 0.f, a5 = 0.f, a6 = 0.f, a7 = 0.f;
  int p0 = off[i], p1 = off[i + 1];
  int pb = p0;
  int Em1 = E - 1;
  unsigned int e0 = epack[min(pb + g, Em1)];
  unsigned int e1 = epack[min(pb + 4 + g, Em1)];
  unsigned int e2 = epack[min(pb + 8 + g, Em1)];
  unsigned int e3 = epack[min(pb + 12 + g, Em1)];
  unsigned int f0 = epack[min(pb + 16 + g, Em1)];
  unsigned int f1 = epack[min(pb + 20 + g, Em1)];
  unsigned int f2 = epack[min(pb + 24 + g, Em1)];
  unsigned int f3 = epack[min(pb + 28 + g, Em1)];
  uint2 H0 = h[(size_t)(e0 >> 16) * 16 + q];
  uint2 H1 = h[(size_t)(e1 >> 16) * 16 + q];
  uint2 H2 = h[(size_t)(e2 >> 16) * 16 + q];
  uint2 H3 = h[(size_t)(e3 >> 16) * 16 + q];
  #define ACC_EDGE(vv, ee)                                                    \
    {                                                                         \
      float n_ = bf2f(ee) * di;                                               \
      f32x2 c0_ = __builtin_amdgcn_cvt_pk_f32_fp8((int)vv.x, false);          \
      f32x2 c1_ = __builtin_amdgcn_cvt_pk_f32_fp8((int)vv.x, true);           \
      f32x2 c2_ = __builtin_amdgcn_cvt_pk_f32_fp8((int)vv.y, false);          \
      f32x2 c3_ = __builtin_amdgcn_cvt_pk_f32_fp8((int)vv.y, true);           \
      a0 += c0_[0] * n_; a1 += c0_[1] * n_;                                   \
      a2 += c1_[0] * n_; a3 += c1_[1] * n_;                                   \
      a4 += c2_[0] * n_; a5 += c2_[1] * n_;                                   \
      a6 += c3_[0] * n_; a7 += c3_[1] * n_;                                   \
    }
  for (; pb + 31 < p1; pb += 16) {
    uint2 G0 = h[(size_t)(f0 >> 16) * 16 + q];
    uint2 G1 = h[(size_t)(f1 >> 16) * 16 + q];
    uint2 G2 = h[(size_t)(f2 >> 16) * 16 + q];
    uint2 G3 = h[(size_t)(f3 >> 16) * 16 + q];
    unsigned int n0 = epack[min(pb + 32 + g, Em1)];
    unsigned int n1 = epack[min(pb + 36 + g, Em1)];
    unsigned int n2 = epack[min(pb + 40 + g, Em1)];
    unsigned int n3 = epack[min(pb + 44 + g, Em1)];
    ACC_EDGE(H0, e0); ACC_EDGE(H1, e1); ACC_EDGE(H2, e2); ACC_EDGE(H3, e3);
    e0 = f0; e1 = f1; e2 = f2; e3 = f3;
    f0 = n0; f1 = n1; f2 = n2; f3 = n3;
    H0 = G0; H1 = G1; H2 = G2; H3 = G3;
  }
  if (pb + g < p1)      ACC_EDGE(H0, e0);
  if (pb + 4 + g < p1)  ACC_EDGE(H1, e1);
  if (pb + 8 + g < p1)  ACC_EDGE(H2, e2);
  if (pb + 12 + g < p1) ACC_EDGE(H3, e3);
  int pc = pb + 16;
  if (pc < p1) {
    uint2 G0 = h[(size_t)(f0 >> 16) * 16 + q];
    uint2 G1 = h[(size_t)(f1 >> 16) * 16 + q];
    uint2 G2 = h[(size_t)(f2 >> 16) * 16 + q];
    uint2 G3 = h[(size_t)(f3 >> 16) * 16 + q];
    if (pc + g < p1)      ACC_EDGE(G0, f0);
    if (pc + 4 + g < p1)  ACC_EDGE(G1, f1);
    if (pc + 8 + g < p1)  ACC_EDGE(G2, f2);
    if (pc + 12 + g < p1) ACC_EDGE(G3, f3);
  }
  #undef ACC_EDGE
  a0 += __shfl_xor(a0, 16); a1 += __shfl_xor(a1, 16);
  a2 += __shfl_xor(a2, 16); a3 += __shfl_xor(a3, 16);
  a4 += __shfl_xor(a4, 16); a5 += __shfl_xor(a5, 16);
  a6 += __shfl_xor(a6, 16); a7 += __shfl_xor(a7, 16);
  a0 += __shfl_xor(a0, 32); a1 += __shfl_xor(a1, 32);
  a2 += __shfl_xor(a2, 32); a3 += __shfl_xor(a3, 32);
  a4 += __shfl_xor(a4, 32); a5 += __shfl_xor(a5, 32);
  a6 += __shfl_xor(a6, 32); a7 += __shfl_xor(a7, 32);
  if (g == 0) {
    uint2 sv = h[(size_t)i * 16 + q];
    float dd = di * di;
    f32x2 s0 = __builtin_amdgcn_cvt_pk_f32_fp8((int)sv.x, false);
    f32x2 s1 = __builtin_amdgcn_cvt_pk_f32_fp8((int)sv.x, true);
    f32x2 s2 = __builtin_amdgcn_cvt_pk_f32_fp8((int)sv.y, false);
    f32x2 s3 = __builtin_amdgcn_cvt_pk_f32_fp8((int)sv.y, true);
    a0 += s0[0] * dd; a1 += s0[1] * dd;
    a2 += s1[0] * dd; a3 += s1[1] * dd;
    a4 += s2[0] * dd; a5 += s2[1] * dd;
    a6 += s3[0] * dd; a7 += s3[1] * dd;
    float4 b0 = ((const float4*)bperm)[q * 2];
    float4 b1v = ((const float4*)bperm)[q * 2 + 1];
    a0 = fmaxf(a0 + b0.x, 0.f); a1 = fmaxf(a1 + b0.y, 0.f);
    a2 = fmaxf(a2 + b0.z, 0.f); a3 = fmaxf(a3 + b0.w, 0.f);
    a4 = fmaxf(a4 + b1v.x, 0.f); a5 = fmaxf(a5 + b1v.y, 0.f);
    a6 = fmaxf(a6 + b1v.z, 0.f); a7 = fmaxf(a7 + b1v.w, 0.f);
    uint4 o;
    o.x = (unsigned int)f2bf(a0) | ((unsigned int)f2bf(a1) << 16);
    o.y = (unsigned int)f2bf(a2) | ((unsigned int)f2bf(a3) << 16);
    o.z = (unsigned int)f2bf(a4) | ((unsigned int)f2bf(a5) << 16);
    o.w = (unsigned int)f2bf(a6) | ((unsigned int)f2bf(a7) << 16);
    outb[(size_t)i * 16 + q] = o;
  }
}

// Layer-2 agg + bias + log_softmax: wave per node, fp8 h2 (uint = 4 ch/lane, 10 lanes/edge),
// 12 edges/iter via 2 gathers, 2-level pipeline.
__global__ void agg2_kernel(const unsigned char* __restrict__ h2, const int* __restrict__ off,
                            const unsigned int* __restrict__ epack,
                            const float* __restrict__ dinv, const float* __restrict__ b,
                            float* __restrict__ out, int n, int E) {
  int wv = threadIdx.x >> 6, l = threadIdx.x & 63;
  int i = blockIdx.x * 4 + wv;
  if (i >= n) return;
  int g = l / 10, q = l - g * 10;
  bool lact = l < 60;
  if (!lact) { g = 0; q = 0; }
  float di = dinv[i];
  float a0 = 0.f, a1 = 0.f, a2 = 0.f, a3 = 0.f;
  int p0 = off[i], p1 = off[i + 1];
  int pb = p0;
  int Em1 = E - 1;
  unsigned int e0 = epack[min(pb + g, Em1)];
  unsigned int e1 = epack[min(pb + 6 + g, Em1)];
  unsigned int f0 = epack[min(pb + 12 + g, Em1)];
  unsigned int f1 = epack[min(pb + 18 + g, Em1)];
  unsigned int H0 = *(const unsigned int*)(h2 + (size_t)(e0 >> 16) * C_OUT + q * 4);
  unsigned int H1 = *(const unsigned int*)(h2 + (size_t)(e1 >> 16) * C_OUT + q * 4);
  #define ACC_EDGE2(vv, ee)                                                   \
    {                                                                         \
      float n_ = bf2f(ee) * di;                                               \
      f32x2 lo_ = __builtin_amdgcn_cvt_pk_f32_fp8((int)(vv), false);          \
      f32x2 hi_ = __builtin_amdgcn_cvt_pk_f32_fp8((int)(vv), true);           \
      a0 += lo_[0] * n_; a1 += lo_[1] * n_;                                   \
      a2 += hi_[0] * n_; a3 += hi_[1] * n_;                                   \
    }
  for (; pb + 23 < p1; pb += 12) {
    unsigned int G0 = *(const unsigned int*)(h2 + (size_t)(f0 >> 16) * C_OUT + q * 4);
    unsigned int G1 = *(const unsigned int*)(h2 + (size_t)(f1 >> 16) * C_OUT + q * 4);
    unsigned int n0 = epack[min(pb + 24 + g, Em1)];
    unsigned int n1 = epack[min(pb + 30 + g, Em1)];
    if (lact) { ACC_EDGE2(H0, e0); ACC_EDGE2(H1, e1); }
    e0 = f0; e1 = f1;
    f0 = n0; f1 = n1;
    H0 = G0; H1 = G1;
  }
  if (lact && pb + g < p1)     ACC_EDGE2(H0, e0);
  if (lact && pb + 6 + g < p1) ACC_EDGE2(H1, e1);
  int pc = pb + 12;
  if (pc < p1) {
    unsigned int G0 = *(const unsigned int*)(h2 + (size_t)(f0 >> 16) * C_OUT + q * 4);
    unsigned int G1 = *(const unsigned int*)(h2 + (size_t)(f1 >> 16) * C_OUT + q * 4);
    if (lact && pc + g < p1)     ACC_EDGE2(G0, f0);
    if (lact && pc + 6 + g < p1) ACC_EDGE2(G1, f1);
  }
  #undef ACC_EDGE2
  float t0 = 0.f, t1 = 0.f, t2 = 0.f, t3 = 0.f;
  #pragma unroll
  for (int gg = 0; gg < 6; ++gg) {
    int sl = gg * 10 + q;
    t0 += __shfl(a0, sl); t1 += __shfl(a1, sl);
    t2 += __shfl(a2, sl); t3 += __shfl(a3, sl);
  }
  bool act = l < 10;
  float v0, v1, v2, v3;
  if (act) {
    unsigned int sv = *(const unsigned int*)(h2 + (size_t)i * C_OUT + l * 4);
    f32x2 slo = __builtin_amdgcn_cvt_pk_f32_fp8((int)sv, false);
    f32x2 shi = __builtin_amdgcn_cvt_pk_f32_fp8((int)sv, true);
    float dd = di * di;
    float4 bb = ((const float4*)b)[l];
    v0 = t0 + slo[0] * dd + bb.x;
    v1 = t1 + slo[1] * dd + bb.y;
    v2 = t2 + shi[0] * dd + bb.z;
    v3 = t3 + shi[1] * dd + bb.w;
  } else {
    v0 = v1 = v2 = v3 = -INFINITY;
  }
  float mm = fmaxf(fmaxf(v0, v1), fmaxf(v2, v3));
  #pragma unroll
  for (int d = 32; d > 0; d >>= 1) mm = fmaxf(mm, __shfl_xor(mm, d));
  float e = act ? (expf(v0 - mm) + expf(v1 - mm) + expf(v2 - mm) + expf(v3 - mm)) : 0.f;
  float ss = e;
  #pragma unroll
  for (int d = 32; d > 0; d >>= 1) ss += __shfl_xor(ss, d);
  if (act) {
    float lg = logf(ss);
    float4 o = {v0 - mm - lg, v1 - mm - lg, v2 - mm - lg, v3 - mm - lg};
    *(float4*)&out[(size_t)i * C_OUT + l * 4] = o;
  }
}

// ---------------- launch ----------------

extern "C" void kernel_launch(void* const* d_in, const int* in_sizes, int n_in,
                              void* d_out, int out_size, void* d_ws, size_t ws_size,
                              hipStream_t stream) {
  const float* x  = (const float*)d_in[0];
  const int*   ei = (const int*)d_in[1];
  const float* W1 = (const float*)d_in[2];
  const float* b1 = (const float*)d_in[3];
  const float* W2 = (const float*)d_in[4];
  const float* b2 = (const float*)d_in[5];
  int E = in_sizes[1] / 2;
  const int* src = ei;
  const int* dst = ei + E;

  char* ws = (char*)d_ws;
  size_t o = 0;
  auto alloc = [&](size_t bytes) {
    char* p = ws + o;
    o += (bytes + 255) & ~(size_t)255;
    return p;
  };
  unsigned int* gedge = (unsigned int*)alloc((size_t)NBUCK * CAP * sizeof(unsigned int));
  int*   bcur  = (int*)alloc(NBUCK * sizeof(int));
  int*   off   = (int*)alloc((NN + 1) * sizeof(int));
  float* dinv  = (float*)alloc(NN * sizeof(float));
  int*   esrc  = (int*)alloc((size_t)E * sizeof(int));
  unsigned int* epck = (unsigned int*)alloc((size_t)E * sizeof(unsigned int));
  uint2* h1f8  = (uint2*)alloc((size_t)NN * C_HID);      // fp8, 128 B/row
  unsigned int*   ag1b = (unsigned int*)alloc((size_t)NN * (C_HID / 2) * sizeof(unsigned int));
  unsigned char*  h2f8 = (unsigned char*)alloc((size_t)NN * C_OUT);  // fp8, 40 B/row
  uint4* pbuf2 = (uint4*)alloc(12 * 64 * sizeof(uint4));
  uint4* pbuf1 = (uint4*)alloc(64 * 64 * sizeof(uint4));
  float* bperm = (float*)alloc(C_HID * sizeof(float));

  int nA  = (E + EPB - 1) / EPB;          // 391 passA blocks
  int ng1 = (NN + 127) / 128;             // 391 gemm1 blocks (128 rows each)
  int ng2 = (NN + 63) / 64;               // 782 gemm2 blocks

  hipMemsetAsync(bcur, 0, NBUCK * sizeof(int), stream);
  prep_passA_kernel<<<20 + nA, 256, 0, stream>>>(W1, W2, b1, pbuf1, pbuf2, bperm,
                                                 src, dst, E, gedge, bcur);
  passB_g1_kernel<<<NBUCK + ng1, 512, 0, stream>>>(gedge, bcur, esrc, off, dinv, E,
                                                   x, pbuf1, h1f8);
  epack_kernel<<<(E + 255) / 256, 256, 0, stream>>>(esrc, dinv, epck, E);
  agg1_kernel<<<(NN + 3) / 4, 256, 0, stream>>>(h1f8, off, epck, dinv, bperm,
                                                (uint4*)ag1b, NN, E);
  gemm2_kernel<<<ng2, 256, 0, stream>>>((const unsigned short*)ag1b, pbuf2, h2f8);
  agg2_kernel<<<(NN + 3) / 4, 256, 0, stream>>>(h2f8, off, epck, dinv, b2,
                                                (float*)d_out, NN, E);
}

// Round 15
// 130.679 us; speedup vs baseline: 1.5077x; 1.0176x over previous
//
#include <hip/hip_runtime.h>
#include <cmath>

#define NN 50000
#define C_IN 256
#define C_HID 128
#define C_OUT 40

#define BSZ 512                          // nodes per bucket
#define NBUCK ((NN + BSZ - 1) / BSZ)     // 98
#define CAP 19456                        // max edges per bucket region
#define EPB 4096                         // edges per passA block

typedef __attribute__((ext_vector_type(8))) short bf16x8;
typedef __attribute__((ext_vector_type(4))) float f32x4;
typedef __attribute__((ext_vector_type(2))) float f32x2;

__device__ __forceinline__ float bf2f(unsigned int u16) {
  unsigned int b = (u16 & 0xFFFFu) << 16;
  return __builtin_bit_cast(float, b);
}
__device__ __forceinline__ unsigned short f2bf(float f) {
  unsigned int b = __builtin_bit_cast(unsigned int, f);
  unsigned int r = (b + 0x7FFF + ((b >> 16) & 1)) >> 16;  // RNE
  return (unsigned short)r;
}

// ---------------- Fused: W prep (+permuted b1) ∥ CSR pass A ------------------------------
// blocks 0-15: W1 frags; 16-18: W2 frags (k-permuted); 19: bperm; 20+: passA.
// bcur must be zeroed before this launch (memset). NO global cnt atomics (R13 lesson).
// h1 stored layout: row pos p = c0*8 + t holds channel chan(p) = (p&7)*16 + (p>>3).

__global__ __launch_bounds__(256) void prep_passA_kernel(const float* __restrict__ W1,
    const float* __restrict__ W2, const float* __restrict__ b1,
    uint4* __restrict__ pbuf1, uint4* __restrict__ pbuf2, float* __restrict__ bperm,
    const int* __restrict__ src, const int* __restrict__ dst, int E,
    unsigned int* __restrict__ gedge, int* __restrict__ bcur) {
  __shared__ unsigned int pk[EPB];
  __shared__ unsigned char bof[EPB];
  __shared__ int bcnt[NBUCK], bstart[NBUCK], bpos[NBUCK], gbase[NBUCK];
  int blk = blockIdx.x;
  int tid = threadIdx.x;
  if (blk < 16) {  // W1
    int gid = blk * 256 + tid;
    int l = gid & 63, idx = gid >> 6;  // idx = t*8+ks
    int ks = idx & 7, t = idx >> 3;
    int c = t * 16 + (l & 15);
    int kbase = ks * 32 + (l >> 4) * 8;
    unsigned int u[4];
    #pragma unroll
    for (int jp = 0; jp < 4; ++jp) {
      float v0 = W1[(size_t)(kbase + 2 * jp) * C_HID + c];
      float v1 = W1[(size_t)(kbase + 2 * jp + 1) * C_HID + c];
      u[jp] = (unsigned int)f2bf(v0) | ((unsigned int)f2bf(v1) << 16);
    }
    pbuf1[idx * 64 + l] = make_uint4(u[0], u[1], u[2], u[3]);
    return;
  } else if (blk < 19) {  // W2, k-permuted to match h1/ag1 stored order
    int gid = (blk - 16) * 256 + tid;
    int l = gid & 63, idx = gid >> 6;  // idx = t*4+ks
    int ks = idx & 3, t = idx >> 2;
    int c = t * 16 + (l & 15);
    int kbase = ks * 32 + (l >> 4) * 8;
    unsigned int u[4];
    #pragma unroll
    for (int jp = 0; jp < 4; ++jp) {
      int k0 = kbase + 2 * jp, k1 = k0 + 1;
      int ch0 = ((k0 & 7) << 4) + (k0 >> 3);
      int ch1 = ((k1 & 7) << 4) + (k1 >> 3);
      float v0 = (c < C_OUT) ? W2[(size_t)ch0 * C_OUT + c] : 0.f;
      float v1 = (c < C_OUT) ? W2[(size_t)ch1 * C_OUT + c] : 0.f;
      u[jp] = (unsigned int)f2bf(v0) | ((unsigned int)f2bf(v1) << 16);
    }
    pbuf2[idx * 64 + l] = make_uint4(u[0], u[1], u[2], u[3]);
    return;
  } else if (blk == 19) {  // permuted bias for agg1
    if (tid < C_HID) bperm[tid] = b1[((tid & 7) << 4) + (tid >> 3)];
    return;
  }
  // ---- passA path (LDS-binned partition; LDS atomics only) ----
  int e0 = (blk - 20) * EPB;
  int cntE = min(EPB, E - e0);
  for (int b = tid; b < NBUCK; b += 256) bcnt[b] = 0;
  int ds_[16], ss_[16];
  __syncthreads();
  #pragma unroll
  for (int k = 0; k < 16; ++k) {
    int i = tid + k * 256;
    if (i < cntE) {
      ds_[k] = dst[e0 + i];
      ss_[k] = src[e0 + i];
      atomicAdd(&bcnt[ds_[k] >> 9], 1);
    }
  }
  __syncthreads();
  if (tid == 0) {
    int acc = 0;
    for (int b = 0; b < NBUCK; ++b) { bstart[b] = acc; bpos[b] = acc; acc += bcnt[b]; }
  }
  __syncthreads();
  #pragma unroll
  for (int k = 0; k < 16; ++k) {
    int i = tid + k * 256;
    if (i < cntE) {
      int b = ds_[k] >> 9;
      int p = atomicAdd(&bpos[b], 1);
      pk[p] = ((unsigned int)ss_[k] << 9) | (unsigned int)(ds_[k] & 511);
      bof[p] = (unsigned char)b;
    }
  }
  __syncthreads();
  for (int b = tid; b < NBUCK; b += 256)
    gbase[b] = atomicAdd(&bcur[b], bcnt[b]);
  __syncthreads();
  for (int i = tid; i < cntE; i += 256) {
    int b = bof[i];
    int p = gbase[b] + (i - bstart[b]);
    gedge[(size_t)b * CAP + p] = pk[i];
  }
}

// ---------------- Fused: pass B (counting sort) ∥ GEMM1 (MFMA) ---------------------------
// blocks 0..NBUCK-1: per-bucket counting sort -> esrc, off, dinv.
// blocks NBUCK..: gemm1, 8 waves x 16 rows = 128 rows/block.

__global__ __launch_bounds__(512) void passB_g1_kernel(const unsigned int* __restrict__ gedge,
    const int* __restrict__ bcur, int* __restrict__ esrc, int* __restrict__ off,
    float* __restrict__ dinv, int E,
    const float* __restrict__ x, const uint4* __restrict__ pb, uint2* __restrict__ h) {
  __shared__ int dcnt[512];
  __shared__ int dsc[512];
  __shared__ int dcur[512];
  __shared__ int bc[128];
  int tid = threadIdx.x;
  if ((int)blockIdx.x >= NBUCK) {
    // ---- GEMM1 path ----
    int l = tid & 63, w = tid >> 6;  // 8 waves
    int row0 = (blockIdx.x - NBUCK) * 128 + w * 16;
    int arow = min(row0 + (l & 15), NN - 1);
    const float* xp = x + (size_t)arow * C_IN + (l >> 4) * 8;
    bf16x8 a[8];
    #pragma unroll
    for (int ks = 0; ks < 8; ++ks) {
      float4 a0 = *(const float4*)(xp + ks * 32);
      float4 a1 = *(const float4*)(xp + ks * 32 + 4);
      union { bf16x8 v; unsigned short s[8]; } pa;
      pa.s[0] = f2bf(a0.x); pa.s[1] = f2bf(a0.y); pa.s[2] = f2bf(a0.z); pa.s[3] = f2bf(a0.w);
      pa.s[4] = f2bf(a1.x); pa.s[5] = f2bf(a1.y); pa.s[6] = f2bf(a1.z); pa.s[7] = f2bf(a1.w);
      a[ks] = pa.v;
    }
    f32x4 acc[8] = {};
    #pragma unroll
    for (int t = 0; t < 8; ++t) {
      #pragma unroll
      for (int ks = 0; ks < 8; ++ks) {
        bf16x8 b = __builtin_bit_cast(bf16x8, pb[(t * 8 + ks) * 64 + l]);
        acc[t] = __builtin_amdgcn_mfma_f32_16x16x32_bf16(a[ks], b, acc[t], 0, 0, 0);
      }
    }
    int c0 = l & 15, rb = (l >> 4) * 4;
    #pragma unroll
    for (int r = 0; r < 4; ++r) {
      int row = row0 + rb + r;
      if (row < NN) {
        int w0 = __builtin_amdgcn_cvt_pk_fp8_f32(acc[0][r], acc[1][r], 0, false);
        w0     = __builtin_amdgcn_cvt_pk_fp8_f32(acc[2][r], acc[3][r], w0, true);
        int w1 = __builtin_amdgcn_cvt_pk_fp8_f32(acc[4][r], acc[5][r], 0, false);
        w1     = __builtin_amdgcn_cvt_pk_fp8_f32(acc[6][r], acc[7][r], w1, true);
        h[(size_t)row * 16 + c0] = make_uint2((unsigned int)w0, (unsigned int)w1);
      }
    }
    return;
  }
  // ---- passB path ----
  int b = blockIdx.x;
  int nE = bcur[b];
  if (tid < 128) bc[tid] = (tid < b) ? bcur[tid] : 0;
  dcnt[tid] = 0;
  __syncthreads();
  const unsigned int* reg = gedge + (size_t)b * CAP;
  for (int i = tid; i < nE; i += 512)
    atomicAdd(&dcnt[reg[i] & 511], 1);
  __syncthreads();
  for (int d = 64; d > 0; d >>= 1) {  // tree-reduce bc -> base
    if (tid < d) bc[tid] += bc[tid + d];
    __syncthreads();
  }
  int base = bc[0];
  int own = dcnt[tid];
  dsc[tid] = own;
  __syncthreads();
  for (int d = 1; d < 512; d <<= 1) {
    int x_ = (tid >= d) ? dsc[tid - d] : 0;
    __syncthreads();
    dsc[tid] += x_;
    __syncthreads();
  }
  int excl = dsc[tid] - own;
  dcur[tid] = excl;
  int node = b * BSZ + tid;
  if (node < NN) {
    off[node]  = base + excl;
    dinv[node] = rsqrtf((float)(own + 1));
  }
  if (b == 0 && tid == 0) off[NN] = E;
  __syncthreads();
  for (int i = tid; i < nE; i += 512) {
    unsigned int p = reg[i];
    int pos = atomicAdd(&dcur[p & 511], 1);
    esrc[base + pos] = (int)(p >> 9);
  }
}

// ---------------- GEMM 2 (MFMA): h2[50000,40](fp8) = ag1(bf16, stored order) @ W2 --------

__global__ __launch_bounds__(256) void gemm2_kernel(const unsigned short* __restrict__ ag1b,
    const uint4* __restrict__ pbuf, unsigned char* __restrict__ h2) {
  int l = threadIdx.x & 63, w = threadIdx.x >> 6;
  int row0 = blockIdx.x * 64 + w * 16;
  int arow = min(row0 + (l & 15), NN - 1);
  const uint4* ap = (const uint4*)(ag1b + (size_t)arow * C_HID + (l >> 4) * 8);
  bf16x8 a[4];
  #pragma unroll
  for (int ks = 0; ks < 4; ++ks) a[ks] = __builtin_bit_cast(bf16x8, ap[ks * 4]);
  f32x4 acc[3] = {};
  #pragma unroll
  for (int t = 0; t < 3; ++t) {
    #pragma unroll
    for (int ks = 0; ks < 4; ++ks) {
      bf16x8 b = __builtin_bit_cast(bf16x8, pbuf[(t * 4 + ks) * 64 + l]);
      acc[t] = __builtin_amdgcn_mfma_f32_16x16x32_bf16(a[ks], b, acc[t], 0, 0, 0);
    }
  }
  int rbase = row0 + (l >> 4) * 4;
  int c0 = l & 15;
  #pragma unroll
  for (int t = 0; t < 3; ++t) {
    int col = t * 16 + c0;
    if (col < C_OUT) {
      #pragma unroll
      for (int r = 0; r < 4; ++r) {
        int row = rbase + r;
        if (row < NN) {
          int pk = __builtin_amdgcn_cvt_pk_fp8_f32(acc[t][r], 0.f, 0, false);
          h2[(size_t)row * C_OUT + col] = (unsigned char)(pk & 0xFF);
        }
      }
    }
  }
}

// ---------------- Aggregation ----------------

// Layer-1 agg: wave per node, 8 lanes/edge (uint4 = 16 fp8 ch), 16 edges/iter via 2 gathers.
// Meta stage = coalesced esrc load (2 ahead); data stage = {h-row, dinv} gathers (1 ahead).
// Output bf16 in stored order.
__global__ void agg1_kernel(const uint4* __restrict__ h, const int* __restrict__ off,
                            const int* __restrict__ esrc, const float* __restrict__ dinv,
                            const float* __restrict__ bperm, uint4* __restrict__ outb,
                            int n, int E) {
  int wv = threadIdx.x >> 6, l = threadIdx.x & 63;
  int i = blockIdx.x * 4 + wv;
  if (i >= n) return;
  int g = l >> 3, j = l & 7;   // g: edge slot (0..7), j: 16B chunk within 128B row
  float di = dinv[i];
  float a[16];
  #pragma unroll
  for (int k = 0; k < 16; ++k) a[k] = 0.f;
  int p0 = off[i], p1 = off[i + 1];
  int pb = p0;
  int Em1 = E - 1;
  // meta t, t+1
  int sA0 = esrc[min(pb + g, Em1)];
  int sB0 = esrc[min(pb + 8 + g, Em1)];
  int sA1 = esrc[min(pb + 16 + g, Em1)];
  int sB1 = esrc[min(pb + 24 + g, Em1)];
  // data t
  uint4 HA = h[(size_t)sA0 * 8 + j];
  uint4 HB = h[(size_t)sB0 * 8 + j];
  float nA = dinv[sA0];
  float nB = dinv[sB0];
  #define ACC_E(vv, nn)                                                       \
    {                                                                         \
      float n_ = (nn) * di;                                                   \
      f32x2 p0_ = __builtin_amdgcn_cvt_pk_f32_fp8((int)vv.x, false);          \
      f32x2 p1_ = __builtin_amdgcn_cvt_pk_f32_fp8((int)vv.x, true);           \
      f32x2 p2_ = __builtin_amdgcn_cvt_pk_f32_fp8((int)vv.y, false);          \
      f32x2 p3_ = __builtin_amdgcn_cvt_pk_f32_fp8((int)vv.y, true);           \
      f32x2 p4_ = __builtin_amdgcn_cvt_pk_f32_fp8((int)vv.z, false);          \
      f32x2 p5_ = __builtin_amdgcn_cvt_pk_f32_fp8((int)vv.z, true);           \
      f32x2 p6_ = __builtin_amdgcn_cvt_pk_f32_fp8((int)vv.w, false);          \
      f32x2 p7_ = __builtin_amdgcn_cvt_pk_f32_fp8((int)vv.w, true);           \
      a[0] += p0_[0] * n_;  a[1] += p0_[1] * n_;                              \
      a[2] += p1_[0] * n_;  a[3] += p1_[1] * n_;                              \
      a[4] += p2_[0] * n_;  a[5] += p2_[1] * n_;                              \
      a[6] += p3_[0] * n_;  a[7] += p3_[1] * n_;                              \
      a[8] += p4_[0] * n_;  a[9] += p4_[1] * n_;                              \
      a[10] += p5_[0] * n_; a[11] += p5_[1] * n_;                             \
      a[12] += p6_[0] * n_; a[13] += p6_[1] * n_;                             \
      a[14] += p7_[0] * n_; a[15] += p7_[1] * n_;                             \
    }
  for (; pb + 31 < p1; pb += 16) {
    uint4 GA = h[(size_t)sA1 * 8 + j];   // data t+1 (meta resident)
    uint4 GB = h[(size_t)sB1 * 8 + j];
    float mA = dinv[sA1];
    float mB = dinv[sB1];
    int tA = esrc[min(pb + 32 + g, Em1)];  // meta t+2 (independent)
    int tB = esrc[min(pb + 40 + g, Em1)];
    ACC_E(HA, nA); ACC_E(HB, nB);
    HA = GA; HB = GB; nA = mA; nB = mB;
    sA1 = tA; sB1 = tB;
  }
  // tail batch 1: edges [pb, pb+16) — data resident
  if (pb + g < p1)     ACC_E(HA, nA);
  if (pb + 8 + g < p1) ACC_E(HB, nB);
  // tail batch 2: edges [pb+16, p1) — meta resident, gather now
  int pc = pb + 16;
  if (pc < p1) {
    uint4 GA = h[(size_t)sA1 * 8 + j];
    uint4 GB = h[(size_t)sB1 * 8 + j];
    float mA = dinv[sA1];
    float mB = dinv[sB1];
    if (pc + g < p1)     ACC_E(GA, mA);
    if (pc + 8 + g < p1) ACC_E(GB, mB);
  }
  #undef ACC_E
  #pragma unroll
  for (int k = 0; k < 16; ++k) {
    a[k] += __shfl_xor(a[k], 8);
    a[k] += __shfl_xor(a[k], 16);
    a[k] += __shfl_xor(a[k], 32);
  }
  if (g == 0) {  // lanes 0..7 finalize 16 channels each (positions 16j..16j+15)
    uint4 sv = h[(size_t)i * 8 + j];
    float dd = di * di;
    f32x2 s0 = __builtin_amdgcn_cvt_pk_f32_fp8((int)sv.x, false);
    f32x2 s1 = __builtin_amdgcn_cvt_pk_f32_fp8((int)sv.x, true);
    f32x2 s2 = __builtin_amdgcn_cvt_pk_f32_fp8((int)sv.y, false);
    f32x2 s3 = __builtin_amdgcn_cvt_pk_f32_fp8((int)sv.y, true);
    f32x2 s4 = __builtin_amdgcn_cvt_pk_f32_fp8((int)sv.z, false);
    f32x2 s5 = __builtin_amdgcn_cvt_pk_f32_fp8((int)sv.z, true);
    f32x2 s6 = __builtin_amdgcn_cvt_pk_f32_fp8((int)sv.w, false);
    f32x2 s7 = __builtin_amdgcn_cvt_pk_f32_fp8((int)sv.w, true);
    a[0] += s0[0] * dd;  a[1] += s0[1] * dd;
    a[2] += s1[0] * dd;  a[3] += s1[1] * dd;
    a[4] += s2[0] * dd;  a[5] += s2[1] * dd;
    a[6] += s3[0] * dd;  a[7] += s3[1] * dd;
    a[8] += s4[0] * dd;  a[9] += s4[1] * dd;
    a[10] += s5[0] * dd; a[11] += s5[1] * dd;
    a[12] += s6[0] * dd; a[13] += s6[1] * dd;
    a[14] += s7[0] * dd; a[15] += s7[1] * dd;
    const float4* bp = (const float4*)bperm + j * 4;
    #pragma unroll
    for (int m = 0; m < 4; ++m) {
      float4 bb = bp[m];
      a[m * 4 + 0] = fmaxf(a[m * 4 + 0] + bb.x, 0.f);
      a[m * 4 + 1] = fmaxf(a[m * 4 + 1] + bb.y, 0.f);
      a[m * 4 + 2] = fmaxf(a[m * 4 + 2] + bb.z, 0.f);
      a[m * 4 + 3] = fmaxf(a[m * 4 + 3] + bb.w, 0.f);
    }
    unsigned int o[8];
    #pragma unroll
    for (int m = 0; m < 8; ++m)
      o[m] = (unsigned int)f2bf(a[2 * m]) | ((unsigned int)f2bf(a[2 * m + 1]) << 16);
    outb[(size_t)i * 16 + j * 2]     = make_uint4(o[0], o[1], o[2], o[3]);
    outb[(size_t)i * 16 + j * 2 + 1] = make_uint4(o[4], o[5], o[6], o[7]);
  }
}

// Layer-2 agg + bias + log_softmax: wave per node, fp8 h2 (uint = 4 ch/lane, 10 lanes/edge),
// 12 edges/iter via 2 gathers; esrc meta 2 ahead, {h2,dinv} data 1 ahead.
__global__ void agg2_kernel(const unsigned char* __restrict__ h2, const int* __restrict__ off,
                            const int* __restrict__ esrc, const float* __restrict__ dinv,
                            const float* __restrict__ b, float* __restrict__ out,
                            int n, int E) {
  int wv = threadIdx.x >> 6, l = threadIdx.x & 63;
  int i = blockIdx.x * 4 + wv;
  if (i >= n) return;
  int g = l / 10, q = l - g * 10;
  bool lact = l < 60;
  if (!lact) { g = 0; q = 0; }
  float di = dinv[i];
  float a0 = 0.f, a1 = 0.f, a2 = 0.f, a3 = 0.f;
  int p0 = off[i], p1 = off[i + 1];
  int pb = p0;
  int Em1 = E - 1;
  int sA0 = esrc[min(pb + g, Em1)];
  int sB0 = esrc[min(pb + 6 + g, Em1)];
  int sA1 = esrc[min(pb + 12 + g, Em1)];
  int sB1 = esrc[min(pb + 18 + g, Em1)];
  unsigned int HA = *(const unsigned int*)(h2 + (size_t)sA0 * C_OUT + q * 4);
  unsigned int HB = *(const unsigned int*)(h2 + (size_t)sB0 * C_OUT + q * 4);
  float nA = dinv[sA0];
  float nB = dinv[sB0];
  #define ACC_E2(vv, nn)                                                      \
    {                                                                         \
      float n_ = (nn) * di;                                                   \
      f32x2 lo_ = __builtin_amdgcn_cvt_pk_f32_fp8((int)(vv), false);          \
      f32x2 hi_ = __builtin_amdgcn_cvt_pk_f32_fp8((int)(vv), true);           \
      a0 += lo_[0] * n_; a1 += lo_[1] * n_;                                   \
      a2 += hi_[0] * n_; a3 += hi_[1] * n_;                                   \
    }
  for (; pb + 23 < p1; pb += 12) {
    unsigned int GA = *(const unsigned int*)(h2 + (size_t)sA1 * C_OUT + q * 4);
    unsigned int GB = *(const unsigned int*)(h2 + (size_t)sB1 * C_OUT + q * 4);
    float mA = dinv[sA1];
    float mB = dinv[sB1];
    int tA = esrc[min(pb + 24 + g, Em1)];
    int tB = esrc[min(pb + 30 + g, Em1)];
    if (lact) { ACC_E2(HA, nA); ACC_E2(HB, nB); }
    HA = GA; HB = GB; nA = mA; nB = mB;
    sA1 = tA; sB1 = tB;
  }
  if (lact && pb + g < p1)     ACC_E2(HA, nA);
  if (lact && pb + 6 + g < p1) ACC_E2(HB, nB);
  int pc = pb + 12;
  if (pc < p1) {
    unsigned int GA = *(const unsigned int*)(h2 + (size_t)sA1 * C_OUT + q * 4);
    unsigned int GB = *(const unsigned int*)(h2 + (size_t)sB1 * C_OUT + q * 4);
    float mA = dinv[sA1];
    float mB = dinv[sB1];
    if (lact && pc + g < p1)     ACC_E2(GA, mA);
    if (lact && pc + 6 + g < p1) ACC_E2(GB, mB);
  }
  #undef ACC_E2
  float t0 = 0.f, t1 = 0.f, t2 = 0.f, t3 = 0.f;
  #pragma unroll
  for (int gg = 0; gg < 6; ++gg) {
    int sl = gg * 10 + q;
    t0 += __shfl(a0, sl); t1 += __shfl(a1, sl);
    t2 += __shfl(a2, sl); t3 += __shfl(a3, sl);
  }
  bool act = l < 10;
  float v0, v1, v2, v3;
  if (act) {
    unsigned int sv = *(const unsigned int*)(h2 + (size_t)i * C_OUT + l * 4);
    f32x2 slo = __builtin_amdgcn_cvt_pk_f32_fp8((int)sv, false);
    f32x2 shi = __builtin_amdgcn_cvt_pk_f32_fp8((int)sv, true);
    float dd = di * di;
    float4 bb = ((const float4*)b)[l];
    v0 = t0 + slo[0] * dd + bb.x;
    v1 = t1 + slo[1] * dd + bb.y;
    v2 = t2 + shi[0] * dd + bb.z;
    v3 = t3 + shi[1] * dd + bb.w;
  } else {
    v0 = v1 = v2 = v3 = -INFINITY;
  }
  float mm = fmaxf(fmaxf(v0, v1), fmaxf(v2, v3));
  #pragma unroll
  for (int d = 32; d > 0; d >>= 1) mm = fmaxf(mm, __shfl_xor(mm, d));
  float e = act ? (expf(v0 - mm) + expf(v1 - mm) + expf(v2 - mm) + expf(v3 - mm)) : 0.f;
  float ss = e;
  #pragma unroll
  for (int d = 32; d > 0; d >>= 1) ss += __shfl_xor(ss, d);
  if (act) {
    float lg = logf(ss);
    float4 o = {v0 - mm - lg, v1 - mm - lg, v2 - mm - lg, v3 - mm - lg};
    *(float4*)&out[(size_t)i * C_OUT + l * 4] = o;
  }
}

// ---------------- launch ----------------

extern "C" void kernel_launch(void* const* d_in, const int* in_sizes, int n_in,
                              void* d_out, int out_size, void* d_ws, size_t ws_size,
                              hipStream_t stream) {
  const float* x  = (const float*)d_in[0];
  const int*   ei = (const int*)d_in[1];
  const float* W1 = (const float*)d_in[2];
  const float* b1 = (const float*)d_in[3];
  const float* W2 = (const float*)d_in[4];
  const float* b2 = (const float*)d_in[5];
  int E = in_sizes[1] / 2;
  const int* src = ei;
  const int* dst = ei + E;

  char* ws = (char*)d_ws;
  size_t o = 0;
  auto alloc = [&](size_t bytes) {
    char* p = ws + o;
    o += (bytes + 255) & ~(size_t)255;
    return p;
  };
  unsigned int* gedge = (unsigned int*)alloc((size_t)NBUCK * CAP * sizeof(unsigned int));
  int*   bcur  = (int*)alloc(NBUCK * sizeof(int));
  int*   off   = (int*)alloc((NN + 1) * sizeof(int));
  float* dinv  = (float*)alloc(NN * sizeof(float));
  int*   esrc  = (int*)alloc((size_t)E * sizeof(int));
  uint2* h1f8  = (uint2*)alloc((size_t)NN * C_HID);      // fp8, 128 B/row
  unsigned int*   ag1b = (unsigned int*)alloc((size_t)NN * (C_HID / 2) * sizeof(unsigned int));
  unsigned char*  h2f8 = (unsigned char*)alloc((size_t)NN * C_OUT);  // fp8, 40 B/row
  uint4* pbuf2 = (uint4*)alloc(12 * 64 * sizeof(uint4));
  uint4* pbuf1 = (uint4*)alloc(64 * 64 * sizeof(uint4));
  float* bperm = (float*)alloc(C_HID * sizeof(float));

  int nA  = (E + EPB - 1) / EPB;          // 391 passA blocks
  int ng1 = (NN + 127) / 128;             // 391 gemm1 blocks (128 rows each)
  int ng2 = (NN + 63) / 64;               // 782 gemm2 blocks

  hipMemsetAsync(bcur, 0, NBUCK * sizeof(int), stream);
  prep_passA_kernel<<<20 + nA, 256, 0, stream>>>(W1, W2, b1, pbuf1, pbuf2, bperm,
                                                 src, dst, E, gedge, bcur);
  passB_g1_kernel<<<NBUCK + ng1, 512, 0, stream>>>(gedge, bcur, esrc, off, dinv, E,
                                                   x, pbuf1, h1f8);
  agg1_kernel<<<(NN + 3) / 4, 256, 0, stream>>>((const uint4*)h1f8, off, esrc, dinv,
                                                bperm, (uint4*)ag1b, NN, E);
  gemm2_kernel<<<ng2, 256, 0, stream>>>((const unsigned short*)ag1b, pbuf2, h2f8);
  agg2_kernel<<<(NN + 3) / 4, 256, 0, stream>>>(h2f8, off, esrc, dinv, b2,
                                                (float*)d_out, NN, E);
}